// Round 6
// baseline (246.304 us; speedup 1.0000x reference)
//
#include <hip/hip_runtime.h>
#include <hip/hip_bf16.h>
#include <hip/hip_fp8.h>
#include <math.h>

// ---------------------------------------------------------------------------
// SE3 warping field: nerf_encode -> 6-layer MLP (skip@4) -> heads -> se3 exp
// Round 6: fp8 e4m3 weights+activations (mfma_f32_16x16x32_fp8_fp8),
// A-frags direct global->reg (L2-resident), B-frags in LDS (fp8, XOR-swizzled,
// baked addresses), 256 rows/block, wave tile 64x64 (acc 4x4).
// Head weights packed pre-scaled x4096 (fp8 subnormal floor), descaled in epi.
// ---------------------------------------------------------------------------

typedef float f32x4 __attribute__((ext_vector_type(4)));

#define NROWS 524288
#define BROWS 256

// packed-weight byte offsets: frag layout [f][s][lane][j] (512 B/frag),
// value = W[m = 16f + (lane&15)][k = 32s + 8(lane>>4) + j]  (same map as r1-r5)
#define P0 0        // L0: K=64  (53 padded)
#define P1 8192     // L1: K=128
#define P2 24576
#define P3 40960
#define P4 57344    // L4: K=192 (53+pad11 | 128)
#define P5 81920
#define PH 98304    // head: m 0..2=Wv*4096, 3..5=Wr*4096, rest 0
#define PTOT 100352

#define QINV (1.0f / 4096.0f)

// LDS byte offsets
#define X0_OFF   0        // [256 rows][64 B fp8], swizzle ((row&7)<<3)
#define XA_OFF   16384    // [256 rows][128 B fp8], swizzle ((row&15)<<3)
#define BIAS_OFF 49152    // 800 floats: l*128+m, head at 768..799
#define SC_OFF   0        // screw [256][32 B] f32 (aliases X0; live after L5)
#define LDS_SZ   52352

// ---------------------------------------------------------------------------
template<int KS, int FAN>
__device__ __forceinline__ float pack_val(const float* __restrict__ W, int idx)
{
    int f  = idx / (KS * 512);
    int r2 = idx % (KS * 512);
    int s  = r2 >> 9, r3 = r2 & 511, ln = r3 >> 3, j = r3 & 7;
    int col = f * 16 + (ln & 15);
    int k   = s * 32 + (ln >> 4) * 8 + j;
    if (FAN == 128) return W[col * 128 + k];
    if (FAN == 53)  return (k < 53) ? W[col * 53 + k] : 0.f;
    if (k < 53)  return W[col * 181 + k];
    if (k < 64)  return 0.f;
    return W[col * 181 + (k - 11)];
}

__global__ void pack_w(const float* __restrict__ W0, const float* __restrict__ W1,
                       const float* __restrict__ W2, const float* __restrict__ W3,
                       const float* __restrict__ W4, const float* __restrict__ W5,
                       const float* __restrict__ Wr, const float* __restrict__ Wv,
                       unsigned char* __restrict__ pk)
{
    int e = blockIdx.x * 256 + threadIdx.x;
    if (e >= PTOT) return;
    float val;
    if (e >= PH) {                                   // head, pre-scaled x4096
        int rem = e - PH;
        int s = rem >> 9, r3 = rem & 511, ln = r3 >> 3, j = r3 & 7;
        int col = ln & 15;
        int k = s * 32 + (ln >> 4) * 8 + j;
        if (col < 3)      val = Wv[col * 128 + k] * 4096.f;
        else if (col < 6) val = Wr[(col - 3) * 128 + k] * 4096.f;
        else              val = 0.f;
    }
    else if (e < P1) val = pack_val<2, 53 >(W0, e - P0);
    else if (e < P2) val = pack_val<4, 128>(W1, e - P1);
    else if (e < P3) val = pack_val<4, 128>(W2, e - P2);
    else if (e < P4) val = pack_val<4, 128>(W3, e - P3);
    else if (e < P5) val = pack_val<6, 181>(W4, e - P4);
    else             val = pack_val<4, 128>(W5, e - P5);
    pk[e] = (unsigned char)__hip_cvt_float_to_fp8(val, __HIP_SATFINITE, __HIP_E4M3);
}

// ---------------------------------------------------------------------------
__device__ __forceinline__ unsigned cvt4_fp8(float a, float b, float c, float d)
{
#if __has_builtin(__builtin_amdgcn_cvt_pk_fp8_f32)
    int v = __builtin_amdgcn_cvt_pk_fp8_f32(a, b, 0, false);
    v = __builtin_amdgcn_cvt_pk_fp8_f32(c, d, v, true);
    return (unsigned)v;
#else
    float2 ab; ab.x = a; ab.y = b;
    float2 cd; cd.x = c; cd.y = d;
    unsigned lo = (unsigned)__hip_cvt_float2_to_fp8x2(ab, __HIP_SATFINITE, __HIP_E4M3);
    unsigned hi = (unsigned)__hip_cvt_float2_to_fp8x2(cd, __HIP_SATFINITE, __HIP_E4M3);
    return lo | (hi << 16);
#endif
}

__device__ __forceinline__ float fsin01(float t) {   // sin(2*pi*t), t in [0,1)
    float r; asm("v_sin_f32 %0, %1" : "=v"(r) : "v"(t)); return r;
}
__device__ __forceinline__ float fcos01(float t) {
    float r; asm("v_cos_f32 %0, %1" : "=v"(r) : "v"(t)); return r;
}

// ---------------------------------------------------------------------------
// One MLP layer (fp8). 8 waves: mfG=w&1 (64 cols), nfG=w>>1 (64 rows).
// acc[mf<4][nf<4]; A from global (L2), B from LDS via baked addrs.
template<int KS, int SPLIT, bool BAR1>
__device__ __forceinline__ void mlp_layer(
    unsigned char* smem, const unsigned char* __restrict__ pkL, int lyr,
    const int* bA, const int* sB,
    int lane, int c, int g, int mfG, int nfG)
{
    f32x4 acc[4][4];
    #pragma unroll
    for (int mf = 0; mf < 4; mf++) {
        f32x4 bb = *(const f32x4*)(smem + BIAS_OFF
                       + (lyr * 128 + mfG * 64 + mf * 16 + g * 4) * 4);
        #pragma unroll
        for (int nf = 0; nf < 4; nf++) acc[mf][nf] = bb;
    }

    const unsigned long long* pA = (const unsigned long long*)pkL;
    #pragma unroll
    for (int s = 0; s < KS; s++) {
        unsigned long long Af[4];
        #pragma unroll
        for (int mf = 0; mf < 4; mf++)
            Af[mf] = pA[((mfG * 4 + mf) * KS + s) * 64 + lane];
        unsigned long long Bf[4];
        #pragma unroll
        for (int nf = 0; nf < 4; nf++) {
            if (s < SPLIT) {
                int row = 64 * nfG + 16 * nf + c;
                Bf[nf] = *(const unsigned long long*)(smem + X0_OFF + row * 64
                              + ((32 * s + 8 * g) ^ ((row & 7) << 3)));
            } else {
                Bf[nf] = *(const unsigned long long*)(smem
                              + (bA[nf] ^ (32 * (s - SPLIT))));
            }
        }
        #pragma unroll
        for (int mf = 0; mf < 4; mf++)
            #pragma unroll
            for (int nf = 0; nf < 4; nf++)
                acc[mf][nf] = __builtin_amdgcn_mfma_f32_16x16x32_fp8_fp8(
                    (long)Af[mf], (long)Bf[nf], acc[mf][nf], 0, 0, 0);
    }

    if (BAR1) __syncthreads();   // all reads of XA done before in-place write

    #pragma unroll
    for (int mf = 0; mf < 4; mf++)
        #pragma unroll
        for (int nf = 0; nf < 4; nf++) {
            f32x4 a = acc[mf][nf];
            unsigned d = cvt4_fp8(fmaxf(a[0], 0.f), fmaxf(a[1], 0.f),
                                  fmaxf(a[2], 0.f), fmaxf(a[3], 0.f));
            *(unsigned*)(smem + (sB[nf] ^ (16 * mf))) = d;
        }
    __syncthreads();
}

// ---------------------------------------------------------------------------
__global__ __launch_bounds__(512, 4)
void se3_fused(const float* __restrict__ pos, const float* __restrict__ dir,
               const float* __restrict__ wcode,
               const float* __restrict__ b0, const float* __restrict__ b1,
               const float* __restrict__ b2, const float* __restrict__ b3,
               const float* __restrict__ b4, const float* __restrict__ b5,
               const float* __restrict__ br, const float* __restrict__ bv,
               const unsigned char* __restrict__ pk,
               float* __restrict__ out)
{
    __shared__ unsigned char smem[LDS_SZ];
    const int tid  = threadIdx.x;
    const int lane = tid & 63;
    const int w    = tid >> 6;
    const int c    = lane & 15;
    const int g    = lane >> 4;
    const int mfG  = w & 1;
    const int nfG  = w >> 1;
    const int r0   = blockIdx.x * BROWS;

    // ---- baked per-thread LDS addresses (reused by every XA layer) ----
    int bA[4], sB[4];
    #pragma unroll
    for (int nf = 0; nf < 4; nf++) {
        int row = 64 * nfG + 16 * nf + c;
        int sw  = (row & 15) << 3;
        bA[nf] = XA_OFF + row * 128 + ((8 * g) ^ (sw & 0x18)) + (sw & 0x60);
        sB[nf] = XA_OFF + row * 128 + ((64 * mfG + 4 * g) ^ sw);
    }

    // ---- stage biases (first 288 threads do <=2 each; overlaps encode) ----
    for (int i = tid; i < 800; i += 512) {
        float v;
        if (i < 768) {
            int l = i >> 7, m = i & 127;
            const float* bp = (l == 0) ? b0 : (l == 1) ? b1 : (l == 2) ? b2
                           : (l == 3) ? b3 : (l == 4) ? b4 : b5;
            v = bp[m];
        } else {
            int m = i - 768;
            v = (m < 3) ? bv[m] : ((m < 6) ? br[m - 3] : 0.f);
        }
        *(float*)(smem + BIAS_OFF + i * 4) = v;
    }

    // ---- encode: X0[row][64 B fp8]; 2 threads/row; 4 x b64 swizzled stores -
    {
        int row = tid >> 1, h = tid & 1;
        int gg = r0 + row;
        float p0 = pos[gg*3+0], p1 = pos[gg*3+1], p2 = pos[gg*3+2];
        float vals[32];
        if (h == 0) {
            #pragma unroll
            for (int j = 0; j < 21; j++) {          // sin cols 0..20
                float p = (j < 7) ? p0 : (j < 14 ? p1 : p2);
                float t = p * (float)(1 << (j % 7));
                t -= floorf(t);
                vals[j] = fsin01(t);
            }
            #pragma unroll
            for (int j = 21; j < 32; j++) {         // cos idx 0..10 -> cols 21..31
                int idx = j - 21;
                float p = (idx < 7) ? p0 : (idx < 14 ? p1 : p2);
                float t = p * (float)(1 << (idx % 7));
                t -= floorf(t);
                vals[j] = fcos01(t);
            }
        } else {
            #pragma unroll
            for (int j = 0; j < 10; j++) {          // cos idx 11..20 -> cols 32..41
                int idx = 11 + j;
                float p = (idx < 14) ? p1 : p2;
                float t = p * (float)(1 << (idx % 7));
                t -= floorf(t);
                vals[j] = fcos01(t);
            }
            vals[10] = p0; vals[11] = p1; vals[12] = p2;   // cols 42..44
            const float4* wc4 = (const float4*)(wcode + (size_t)gg * 8);
            float4 wa = wc4[0], wb = wc4[1];
            vals[13] = wa.x; vals[14] = wa.y; vals[15] = wa.z; vals[16] = wa.w;
            vals[17] = wb.x; vals[18] = wb.y; vals[19] = wb.z; vals[20] = wb.w;
            #pragma unroll
            for (int j = 21; j < 32; j++) vals[j] = 0.f;   // cols 53..63
        }
        unsigned dw[8];
        #pragma unroll
        for (int q = 0; q < 8; q++)
            dw[q] = cvt4_fp8(vals[4*q], vals[4*q+1], vals[4*q+2], vals[4*q+3]);
        int swx = (row & 7) << 3;
        unsigned char* base = smem + X0_OFF + row * 64;
        #pragma unroll
        for (int i = 0; i < 4; i++) {
            uint2 u; u.x = dw[2*i]; u.y = dw[2*i+1];
            *(uint2*)(base + ((32 * h + 8 * i) ^ swx)) = u;
        }
    }
    __syncthreads();

    // ---- MLP stem (in-place XA, fp8) ----
    mlp_layer<2,2,false>(smem, pk + P0, 0, bA, sB, lane, c, g, mfG, nfG);
    mlp_layer<4,0,true >(smem, pk + P1, 1, bA, sB, lane, c, g, mfG, nfG);
    mlp_layer<4,0,true >(smem, pk + P2, 2, bA, sB, lane, c, g, mfG, nfG);
    mlp_layer<4,0,true >(smem, pk + P3, 3, bA, sB, lane, c, g, mfG, nfG);
    mlp_layer<6,2,true >(smem, pk + P4, 4, bA, sB, lane, c, g, mfG, nfG); // skip
    mlp_layer<4,0,true >(smem, pk + P5, 5, bA, sB, lane, c, g, mfG, nfG);

    // ---- head: screw = [v(3) | r(3)] * QINV + bias; mfG==0 waves ----
    if (mfG == 0) {
        const unsigned long long* pA = (const unsigned long long*)(pk + PH);
        f32x4 ha[4];
        #pragma unroll
        for (int nf = 0; nf < 4; nf++) ha[nf] = f32x4{0.f, 0.f, 0.f, 0.f};
        #pragma unroll
        for (int s = 0; s < 4; s++) {
            unsigned long long Ah = pA[s * 64 + lane];
            #pragma unroll
            for (int nf = 0; nf < 4; nf++) {
                unsigned long long Bf = *(const unsigned long long*)(smem
                                           + (bA[nf] ^ (32 * s)));
                ha[nf] = __builtin_amdgcn_mfma_f32_16x16x32_fp8_fp8(
                    (long)Ah, (long)Bf, ha[nf], 0, 0, 0);
            }
        }
        f32x4 hb = *(const f32x4*)(smem + BIAS_OFF + (768 + g * 4) * 4);
        #pragma unroll
        for (int nf = 0; nf < 4; nf++) {
            int row = 64 * nfG + 16 * nf + c;
            if (g == 0) {
                f32x4 sc;
                #pragma unroll
                for (int r = 0; r < 4; r++) sc[r] = ha[nf][r] * QINV + hb[r];
                *(f32x4*)(smem + SC_OFF + row * 32) = sc;          // v0,v1,v2,w0
            } else if (g == 1) {
                float* sp = (float*)(smem + SC_OFF + row * 32);
                sp[4] = ha[nf][0] * QINV + hb[0];                  // w1
                sp[5] = ha[nf][1] * QINV + hb[1];                  // w2
            }
        }
    }
    __syncthreads();

    // ---- se3 exp map epilogue (fp32, 1 thread per row, tid<256) ----
    if (tid < BROWS) {
        int row = tid, gg = r0 + row;
        const float* sc = (const float*)(smem + SC_OFF + row * 32);
        float v0 = sc[0], v1 = sc[1], v2 = sc[2];
        float wx = sc[3], wy = sc[4], wz = sc[5];
        float ang2 = wx*wx + wy*wy + wz*wz;
        ang2 = fmaxf(ang2, 1e-4f);               // jnp.clip(.., eps)
        float ang = sqrtf(ang2);
        float sn = __sinf(ang), cs = __cosf(ang);
        float f1 = sn / ang;
        float f2 = (1.f - cs) / ang2;
        float f3 = (ang - sn) / (ang * ang2);
        float K[3][3] = {{0.f,  wz, -wy}, {-wz, 0.f,  wx}, { wy, -wx, 0.f}};
        float KK[3][3];
        #pragma unroll
        for (int i = 0; i < 3; i++)
            #pragma unroll
            for (int j = 0; j < 3; j++)
                KK[i][j] = K[i][0]*K[0][j] + K[i][1]*K[1][j] + K[i][2]*K[2][j];
        float R[3][3], V[3][3];
        #pragma unroll
        for (int i = 0; i < 3; i++)
            #pragma unroll
            for (int j = 0; j < 3; j++) {
                float id = (i == j) ? 1.f : 0.f;
                R[i][j] = id + f1 * K[i][j] + f2 * KK[i][j];
                V[i][j] = id + f2 * K[i][j] + f3 * KK[i][j];
            }
        float T0 = V[0][0]*v0 + V[0][1]*v1 + V[0][2]*v2;
        float T1 = V[1][0]*v0 + V[1][1]*v1 + V[1][2]*v2;
        float T2 = V[2][0]*v0 + V[2][1]*v1 + V[2][2]*v2;
        float px = pos[gg*3+0], py = pos[gg*3+1], pz = pos[gg*3+2];
        float dx = dir[gg*3+0], dy = dir[gg*3+1], dz = dir[gg*3+2];
        // M_rot = R^T : wp[i] = sum_j R[j][i]*p[j] + T[i]
        float wpx = R[0][0]*px + R[1][0]*py + R[2][0]*pz + T0;
        float wpy = R[0][1]*px + R[1][1]*py + R[2][1]*pz + T1;
        float wpz = R[0][2]*px + R[1][2]*py + R[2][2]*pz + T2;
        float wdx = R[0][0]*dx + R[1][0]*dy + R[2][0]*dz;
        float wdy = R[0][1]*dx + R[1][1]*dy + R[2][1]*dz;
        float wdz = R[0][2]*dx + R[1][2]*dy + R[2][2]*dz;
        wpx = (wpx != wpx) ? px : wpx;
        wpy = (wpy != wpy) ? py : wpy;
        wpz = (wpz != wpz) ? pz : wpz;
        wdx = (wdx != wdx) ? dx : wdx;
        wdy = (wdy != wdy) ? dy : wdy;
        wdz = (wdz != wdz) ? dz : wdz;
        out[gg*3+0] = wpx; out[gg*3+1] = wpy; out[gg*3+2] = wpz;
        float* o2 = out + (size_t)NROWS * 3;
        o2[gg*3+0] = wdx; o2[gg*3+1] = wdy; o2[gg*3+2] = wdz;
    }
}

// ---------------------------------------------------------------------------
extern "C" void kernel_launch(void* const* d_in, const int* in_sizes, int n_in,
                              void* d_out, int out_size, void* d_ws, size_t ws_size,
                              hipStream_t stream)
{
    const float* pos = (const float*)d_in[0];
    const float* dir = (const float*)d_in[1];
    const float* wc  = (const float*)d_in[2];
    const float* W0 = (const float*)d_in[3];  const float* b0 = (const float*)d_in[4];
    const float* W1 = (const float*)d_in[5];  const float* b1 = (const float*)d_in[6];
    const float* W2 = (const float*)d_in[7];  const float* b2 = (const float*)d_in[8];
    const float* W3 = (const float*)d_in[9];  const float* b3 = (const float*)d_in[10];
    const float* W4 = (const float*)d_in[11]; const float* b4 = (const float*)d_in[12];
    const float* W5 = (const float*)d_in[13]; const float* b5 = (const float*)d_in[14];
    const float* Wr = (const float*)d_in[15]; const float* br = (const float*)d_in[16];
    const float* Wv = (const float*)d_in[17]; const float* bv = (const float*)d_in[18];
    unsigned char* pkb = (unsigned char*)d_ws;
    float* out = (float*)d_out;

    pack_w<<<(PTOT + 255) / 256, 256, 0, stream>>>(W0, W1, W2, W3, W4, W5, Wr, Wv, pkb);
    se3_fused<<<NROWS / BROWS, 512, 0, stream>>>(pos, dir, wc,
                                                 b0, b1, b2, b3, b4, b5,
                                                 br, bv, pkb, out);
}

// Round 7
// 203.078 us; speedup vs baseline: 1.2129x; 1.2129x over previous
//
#include <hip/hip_runtime.h>
#include <hip/hip_bf16.h>
#include <hip/hip_fp8.h>
#include <math.h>

// ---------------------------------------------------------------------------
// SE3 warping field: nerf_encode -> 6-layer MLP (skip@4) -> heads -> se3 exp
// Round 7: lean fp8 kernel. 256 thr / 4 waves, BROWS=64, wave tile 32x64
// (acc 2x4 = 32 VGPR -> no spills), LDS 12KB -> ~6 blocks/CU (75% occ).
// W direct global->reg (read once per block), biases direct global->acc.
// Proven R6 pieces: fp8 pack (head x4096), k=32s+8g+j byte map, XOR swizzles.
// ---------------------------------------------------------------------------

typedef float f32x4 __attribute__((ext_vector_type(4)));
typedef unsigned long long u64;

#define NROWS 524288
#define BROWS 64

// packed-weight byte offsets: frag layout [f][s][lane][j] (512 B/frag),
// value = W[m = 16f + (lane&15)][k = 32s + 8(lane>>4) + j]
#define P0 0        // L0: K=64  (53 padded)
#define P1 8192     // L1: K=128
#define P2 24576
#define P3 40960
#define P4 57344    // L4: K=192 (53+pad11 | 128)
#define P5 81920
#define PH 98304    // head: m 0..2=Wv*4096, 3..5=Wr*4096, rest 0
#define PTOT 100352

#define QINV (1.0f / 4096.0f)

// LDS byte offsets
#define X0_OFF 0        // [64 rows][64 B fp8],  swizzle ((row&7)<<3)
#define XA_OFF 4096     // [64 rows][128 B fp8], swizzle ((row&15)<<3)
#define SC_OFF 0        // screw [64][32 B] f32 (aliases X0; live after L5)
#define LDS_SZ 12288

// ---------------------------------------------------------------------------
template<int KS, int FAN>
__device__ __forceinline__ float pack_val(const float* __restrict__ W, int idx)
{
    int f  = idx / (KS * 512);
    int r2 = idx % (KS * 512);
    int s  = r2 >> 9, r3 = r2 & 511, ln = r3 >> 3, j = r3 & 7;
    int col = f * 16 + (ln & 15);
    int k   = s * 32 + (ln >> 4) * 8 + j;
    if (FAN == 128) return W[col * 128 + k];
    if (FAN == 53)  return (k < 53) ? W[col * 53 + k] : 0.f;
    if (k < 53)  return W[col * 181 + k];
    if (k < 64)  return 0.f;
    return W[col * 181 + (k - 11)];
}

__global__ void pack_w(const float* __restrict__ W0, const float* __restrict__ W1,
                       const float* __restrict__ W2, const float* __restrict__ W3,
                       const float* __restrict__ W4, const float* __restrict__ W5,
                       const float* __restrict__ Wr, const float* __restrict__ Wv,
                       unsigned char* __restrict__ pk)
{
    int e = blockIdx.x * 256 + threadIdx.x;
    if (e >= PTOT) return;
    float val;
    if (e >= PH) {                                   // head, pre-scaled x4096
        int rem = e - PH;
        int s = rem >> 9, r3 = rem & 511, ln = r3 >> 3, j = r3 & 7;
        int col = ln & 15;
        int k = s * 32 + (ln >> 4) * 8 + j;
        if (col < 3)      val = Wv[col * 128 + k] * 4096.f;
        else if (col < 6) val = Wr[(col - 3) * 128 + k] * 4096.f;
        else              val = 0.f;
    }
    else if (e < P1) val = pack_val<2, 53 >(W0, e - P0);
    else if (e < P2) val = pack_val<4, 128>(W1, e - P1);
    else if (e < P3) val = pack_val<4, 128>(W2, e - P2);
    else if (e < P4) val = pack_val<4, 128>(W3, e - P3);
    else if (e < P5) val = pack_val<6, 181>(W4, e - P4);
    else             val = pack_val<4, 128>(W5, e - P5);
    pk[e] = (unsigned char)__hip_cvt_float_to_fp8(val, __HIP_SATFINITE, __HIP_E4M3);
}

// ---------------------------------------------------------------------------
__device__ __forceinline__ unsigned cvt4_fp8(float a, float b, float c, float d)
{
#if __has_builtin(__builtin_amdgcn_cvt_pk_fp8_f32)
    int v = __builtin_amdgcn_cvt_pk_fp8_f32(a, b, 0, false);
    v = __builtin_amdgcn_cvt_pk_fp8_f32(c, d, v, true);
    return (unsigned)v;
#else
    float2 ab; ab.x = a; ab.y = b;
    float2 cd; cd.x = c; cd.y = d;
    unsigned lo = (unsigned)__hip_cvt_float2_to_fp8x2(ab, __HIP_SATFINITE, __HIP_E4M3);
    unsigned hi = (unsigned)__hip_cvt_float2_to_fp8x2(cd, __HIP_SATFINITE, __HIP_E4M3);
    return lo | (hi << 16);
#endif
}

__device__ __forceinline__ float fsin01(float t) {   // sin(2*pi*t), t in [0,1)
    float r; asm("v_sin_f32 %0, %1" : "=v"(r) : "v"(t)); return r;
}
__device__ __forceinline__ float fcos01(float t) {
    float r; asm("v_cos_f32 %0, %1" : "=v"(r) : "v"(t)); return r;
}
__device__ __forceinline__ float enc_sin(float p, int f) {
    float t = p * (float)(1 << f); t -= floorf(t); return fsin01(t);
}
__device__ __forceinline__ float enc_cos(float p, int f) {
    float t = p * (float)(1 << f); t -= floorf(t); return fcos01(t);
}

// ---------------------------------------------------------------------------
// One MLP layer (fp8). 4 waves: wave w owns out-cols [32w, 32w+32), all 64
// batch rows. acc[mf<2][nf<4]. A from global (L2-resident, read once per
// block), B from LDS via baked swizzled addresses, bias direct from global.
template<int KS, int SPLIT, bool BAR1>
__device__ __forceinline__ void mlp_layer(
    unsigned char* smem, const unsigned char* __restrict__ pkL,
    const float* __restrict__ bl,
    const int* bA, const int* sB, const int* x0A,
    int lane, int g, int w)
{
    f32x4 acc[2][4];
    #pragma unroll
    for (int mf = 0; mf < 2; mf++) {
        f32x4 bb = *(const f32x4*)(bl + 32 * w + 16 * mf + 4 * g);
        #pragma unroll
        for (int nf = 0; nf < 4; nf++) acc[mf][nf] = bb;
    }

    const u64* pA = (const u64*)pkL;
    #pragma unroll
    for (int s = 0; s < KS; s++) {
        u64 Af[2];
        #pragma unroll
        for (int mf = 0; mf < 2; mf++)
            Af[mf] = pA[((w * 2 + mf) * KS + s) * 64 + lane];
        u64 Bf[4];
        #pragma unroll
        for (int nf = 0; nf < 4; nf++) {
            if (s < SPLIT)
                Bf[nf] = *(const u64*)(smem + (x0A[nf] ^ (32 * s)));
            else
                Bf[nf] = *(const u64*)(smem + (bA[nf] ^ (32 * (s - SPLIT))));
        }
        #pragma unroll
        for (int mf = 0; mf < 2; mf++)
            #pragma unroll
            for (int nf = 0; nf < 4; nf++)
                acc[mf][nf] = __builtin_amdgcn_mfma_f32_16x16x32_fp8_fp8(
                    (long)Af[mf], (long)Bf[nf], acc[mf][nf], 0, 0, 0);
    }

    if (BAR1) __syncthreads();   // all waves' reads of XA done before overwrite

    #pragma unroll
    for (int mf = 0; mf < 2; mf++)
        #pragma unroll
        for (int nf = 0; nf < 4; nf++) {
            f32x4 a = acc[mf][nf];
            unsigned d = cvt4_fp8(fmaxf(a[0], 0.f), fmaxf(a[1], 0.f),
                                  fmaxf(a[2], 0.f), fmaxf(a[3], 0.f));
            *(unsigned*)(smem + (sB[nf] ^ (16 * mf))) = d;
        }
    __syncthreads();
}

// ---------------------------------------------------------------------------
__global__ __launch_bounds__(256, 4)
void se3_fused(const float* __restrict__ pos, const float* __restrict__ dir,
               const float* __restrict__ wcode,
               const float* __restrict__ b0, const float* __restrict__ b1,
               const float* __restrict__ b2, const float* __restrict__ b3,
               const float* __restrict__ b4, const float* __restrict__ b5,
               const float* __restrict__ br, const float* __restrict__ bv,
               const unsigned char* __restrict__ pk,
               float* __restrict__ out)
{
    __shared__ unsigned char smem[LDS_SZ];
    const int tid  = threadIdx.x;
    const int lane = tid & 63;
    const int w    = tid >> 6;
    const int c    = lane & 15;
    const int g    = lane >> 4;
    const int r0   = blockIdx.x * BROWS;

    // ---- baked per-thread LDS addresses (all XA/X0 layers reuse) ----
    int bA[4], sB[4], x0A[4];
    #pragma unroll
    for (int nf = 0; nf < 4; nf++) {
        int row = 16 * nf + c;
        int sw4 = (row & 15) << 3;
        int sw3 = (row & 7) << 3;
        bA[nf]  = XA_OFF + row * 128 + ((8 * g) ^ sw4);
        sB[nf]  = XA_OFF + row * 128 + ((32 * w + 4 * g) ^ sw4);
        x0A[nf] = X0_OFF + row * 64  + ((8 * g) ^ sw3);
    }

    // ---- encode: 4 threads/row, thread h covers cols [16h, 16h+16) ----
    {
        int row = tid >> 2, h = tid & 3;
        int gg = r0 + row;
        float p0 = pos[gg*3+0], p1 = pos[gg*3+1], p2 = pos[gg*3+2];
        float vals[16];
        if (h == 0) {            // sin: p0 f0-6, p1 f0-6, p2 f0-1
            #pragma unroll
            for (int f = 0; f < 7; f++) vals[f]     = enc_sin(p0, f);
            #pragma unroll
            for (int f = 0; f < 7; f++) vals[7+f]   = enc_sin(p1, f);
            #pragma unroll
            for (int f = 0; f < 2; f++) vals[14+f]  = enc_sin(p2, f);
        } else if (h == 1) {     // sin p2 f2-6; cos p0 f0-6, p1 f0-3
            #pragma unroll
            for (int f = 2; f < 7; f++) vals[f-2]   = enc_sin(p2, f);
            #pragma unroll
            for (int f = 0; f < 7; f++) vals[5+f]   = enc_cos(p0, f);
            #pragma unroll
            for (int f = 0; f < 4; f++) vals[12+f]  = enc_cos(p1, f);
        } else if (h == 2) {     // cos p1 f4-6, p2 f0-6; p3; wc0-2
            #pragma unroll
            for (int f = 4; f < 7; f++) vals[f-4]   = enc_cos(p1, f);
            #pragma unroll
            for (int f = 0; f < 7; f++) vals[3+f]   = enc_cos(p2, f);
            vals[10] = p0; vals[11] = p1; vals[12] = p2;
            const float4* wc4 = (const float4*)(wcode + (size_t)gg * 8);
            float4 wa = wc4[0];
            vals[13] = wa.x; vals[14] = wa.y; vals[15] = wa.z;
        } else {                 // wc3-7; zeros
            const float4* wc4 = (const float4*)(wcode + (size_t)gg * 8);
            float4 wa = wc4[0], wb = wc4[1];
            vals[0] = wa.w;
            vals[1] = wb.x; vals[2] = wb.y; vals[3] = wb.z; vals[4] = wb.w;
            #pragma unroll
            for (int q = 5; q < 16; q++) vals[q] = 0.f;
        }
        unsigned dw[4];
        #pragma unroll
        for (int q = 0; q < 4; q++)
            dw[q] = cvt4_fp8(vals[4*q], vals[4*q+1], vals[4*q+2], vals[4*q+3]);
        int sw = (row & 7) << 3;
        unsigned char* base = smem + X0_OFF + row * 64;
        uint2 ua; ua.x = dw[0]; ua.y = dw[1];
        uint2 ub; ub.x = dw[2]; ub.y = dw[3];
        *(uint2*)(base + ((16 * h)     ^ sw)) = ua;   // 8B-granular swizzle-
        *(uint2*)(base + ((16 * h + 8) ^ sw)) = ub;   // consistent stores
    }
    __syncthreads();

    // ---- MLP stem (in-place XA, fp8) ----
    mlp_layer<2,2,false>(smem, pk + P0, b0, bA, sB, x0A, lane, g, w);
    mlp_layer<4,0,true >(smem, pk + P1, b1, bA, sB, x0A, lane, g, w);
    mlp_layer<4,0,true >(smem, pk + P2, b2, bA, sB, x0A, lane, g, w);
    mlp_layer<4,0,true >(smem, pk + P3, b3, bA, sB, x0A, lane, g, w);
    mlp_layer<6,2,true >(smem, pk + P4, b4, bA, sB, x0A, lane, g, w); // skip
    mlp_layer<4,0,true >(smem, pk + P5, b5, bA, sB, x0A, lane, g, w);

    // ---- head (wave 0 only): screw = [v(3) | r(3)] * QINV + bias ----
    if (w == 0) {
        const u64* pA = (const u64*)(pk + PH);
        f32x4 ha[4];
        #pragma unroll
        for (int nf = 0; nf < 4; nf++) ha[nf] = f32x4{0.f, 0.f, 0.f, 0.f};
        #pragma unroll
        for (int s = 0; s < 4; s++) {
            u64 Ah = pA[s * 64 + lane];
            #pragma unroll
            for (int nf = 0; nf < 4; nf++) {
                u64 Bf = *(const u64*)(smem + (bA[nf] ^ (32 * s)));
                ha[nf] = __builtin_amdgcn_mfma_f32_16x16x32_fp8_fp8(
                    (long)Ah, (long)Bf, ha[nf], 0, 0, 0);
            }
        }
        // lane (c,g) holds head rows m = 4g+r for batch row 16nf+c
        float bv0 = bv[0], bv1 = bv[1], bv2 = bv[2];
        float br0 = br[0], br1 = br[1], br2 = br[2];
        #pragma unroll
        for (int nf = 0; nf < 4; nf++) {
            int row = 16 * nf + c;
            if (g == 0) {
                f32x4 scv;
                scv[0] = ha[nf][0] * QINV + bv0;   // v0
                scv[1] = ha[nf][1] * QINV + bv1;   // v1
                scv[2] = ha[nf][2] * QINV + bv2;   // v2
                scv[3] = ha[nf][3] * QINV + br0;   // wx
                *(f32x4*)(smem + SC_OFF + row * 32) = scv;
            } else if (g == 1) {
                float* sp = (float*)(smem + SC_OFF + row * 32);
                sp[4] = ha[nf][0] * QINV + br1;    // wy
                sp[5] = ha[nf][1] * QINV + br2;    // wz
            }
        }
    }
    __syncthreads();

    // ---- se3 exp map epilogue (fp32, 1 thread per row) ----
    if (tid < BROWS) {
        int row = tid, gg = r0 + row;
        const float* sc = (const float*)(smem + SC_OFF + row * 32);
        float v0 = sc[0], v1 = sc[1], v2 = sc[2];
        float wx = sc[3], wy = sc[4], wz = sc[5];
        float ang2 = wx*wx + wy*wy + wz*wz;
        ang2 = fmaxf(ang2, 1e-4f);               // jnp.clip(.., eps)
        float ang = sqrtf(ang2);
        float sn = __sinf(ang), cs = __cosf(ang);
        float f1 = sn / ang;
        float f2 = (1.f - cs) / ang2;
        float f3 = (ang - sn) / (ang * ang2);
        float K[3][3] = {{0.f,  wz, -wy}, {-wz, 0.f,  wx}, { wy, -wx, 0.f}};
        float KK[3][3];
        #pragma unroll
        for (int i = 0; i < 3; i++)
            #pragma unroll
            for (int j = 0; j < 3; j++)
                KK[i][j] = K[i][0]*K[0][j] + K[i][1]*K[1][j] + K[i][2]*K[2][j];
        float R[3][3], V[3][3];
        #pragma unroll
        for (int i = 0; i < 3; i++)
            #pragma unroll
            for (int j = 0; j < 3; j++) {
                float id = (i == j) ? 1.f : 0.f;
                R[i][j] = id + f1 * K[i][j] + f2 * KK[i][j];
                V[i][j] = id + f2 * K[i][j] + f3 * KK[i][j];
            }
        float T0 = V[0][0]*v0 + V[0][1]*v1 + V[0][2]*v2;
        float T1 = V[1][0]*v0 + V[1][1]*v1 + V[1][2]*v2;
        float T2 = V[2][0]*v0 + V[2][1]*v1 + V[2][2]*v2;
        float px = pos[gg*3+0], py = pos[gg*3+1], pz = pos[gg*3+2];
        float dx = dir[gg*3+0], dy = dir[gg*3+1], dz = dir[gg*3+2];
        // M_rot = R^T : wp[i] = sum_j R[j][i]*p[j] + T[i]
        float wpx = R[0][0]*px + R[1][0]*py + R[2][0]*pz + T0;
        float wpy = R[0][1]*px + R[1][1]*py + R[2][1]*pz + T1;
        float wpz = R[0][2]*px + R[1][2]*py + R[2][2]*pz + T2;
        float wdx = R[0][0]*dx + R[1][0]*dy + R[2][0]*dz;
        float wdy = R[0][1]*dx + R[1][1]*dy + R[2][1]*dz;
        float wdz = R[0][2]*dx + R[1][2]*dy + R[2][2]*dz;
        wpx = (wpx != wpx) ? px : wpx;
        wpy = (wpy != wpy) ? py : wpy;
        wpz = (wpz != wpz) ? pz : wpz;
        wdx = (wdx != wdx) ? dx : wdx;
        wdy = (wdy != wdy) ? dy : wdy;
        wdz = (wdz != wdz) ? dz : wdz;
        out[gg*3+0] = wpx; out[gg*3+1] = wpy; out[gg*3+2] = wpz;
        float* o2 = out + (size_t)NROWS * 3;
        o2[gg*3+0] = wdx; o2[gg*3+1] = wdy; o2[gg*3+2] = wdz;
    }
}

// ---------------------------------------------------------------------------
extern "C" void kernel_launch(void* const* d_in, const int* in_sizes, int n_in,
                              void* d_out, int out_size, void* d_ws, size_t ws_size,
                              hipStream_t stream)
{
    const float* pos = (const float*)d_in[0];
    const float* dir = (const float*)d_in[1];
    const float* wc  = (const float*)d_in[2];
    const float* W0 = (const float*)d_in[3];  const float* b0 = (const float*)d_in[4];
    const float* W1 = (const float*)d_in[5];  const float* b1 = (const float*)d_in[6];
    const float* W2 = (const float*)d_in[7];  const float* b2 = (const float*)d_in[8];
    const float* W3 = (const float*)d_in[9];  const float* b3 = (const float*)d_in[10];
    const float* W4 = (const float*)d_in[11]; const float* b4 = (const float*)d_in[12];
    const float* W5 = (const float*)d_in[13]; const float* b5 = (const float*)d_in[14];
    const float* Wr = (const float*)d_in[15]; const float* br = (const float*)d_in[16];
    const float* Wv = (const float*)d_in[17]; const float* bv = (const float*)d_in[18];
    unsigned char* pkb = (unsigned char*)d_ws;
    float* out = (float*)d_out;

    pack_w<<<(PTOT + 255) / 256, 256, 0, stream>>>(W0, W1, W2, W3, W4, W5, Wr, Wv, pkb);
    se3_fused<<<NROWS / BROWS, 256, 0, stream>>>(pos, dir, wc,
                                                 b0, b1, b2, b3, b4, b5,
                                                 br, bv, pkb, out);
}